// Round 8
// baseline (333.527 us; speedup 1.0000x reference)
//
#include <hip/hip_runtime.h>
#include <hip/hip_bf16.h>

typedef __hip_bfloat16 bf16;
typedef short bf16x8_t __attribute__((ext_vector_type(8)));  // 8 bf16 = 4 VGPRs
typedef short s4_t __attribute__((ext_vector_type(4)));      // 4 bf16 = 8B
typedef float f32x4_t __attribute__((ext_vector_type(4)));

#define NTOK 8192
#define INF  1024
#define OUTF 1024
#define GS   8
#define KTOT (INF + INF * GS)  // 9216

union b8u { bf16 h[8]; bf16x8_t v; };
union b4u { bf16 h[4]; ushort2 v2[2]; };
union b4s { bf16 h[4]; s4_t v; };

// ---------------- prep: A_base (silu only, 17MB) + B ------------------------------
// Spline region of A (134MB) is no longer materialized — produced inside the GEMM.
#define PA ((NTOK * INF / 4) / 256)   // 8192 blocks (4 elems/thread)
#define PB ((OUTF * INF * 2) / 256)   // 8192 blocks

__global__ __launch_bounds__(256) void prep_fused(const float* __restrict__ x,
                                                  const float* __restrict__ bw,
                                                  const float* __restrict__ sw,
                                                  const float* __restrict__ ss,
                                                  bf16* __restrict__ A,
                                                  bf16* __restrict__ B) {
  const int b = blockIdx.x;
  if (b < PA) {
    const int tid = b * 256 + threadIdx.x;      // 0 .. NTOK*INF/4-1
    const float4 x4 = ((const float4*)x)[tid];
    b4s sil;
    sil.h[0] = __float2bfloat16(x4.x / (1.0f + __expf(-x4.x)));
    sil.h[1] = __float2bfloat16(x4.y / (1.0f + __expf(-x4.y)));
    sil.h[2] = __float2bfloat16(x4.z / (1.0f + __expf(-x4.z)));
    sil.h[3] = __float2bfloat16(x4.w / (1.0f + __expf(-x4.w)));
    *(s4_t*)(A + (size_t)tid * 4) = sil.v;      // A_base row stride = INF
  } else {
    const int tid = (b - PA) * 256 + threadIdx.x;  // 0 .. OUTF*INF*2-1
    const int o = tid >> 11;
    const int r = tid & 2047;
    const float4 w4 = ((const float4*)sw)[tid];
    const float sc = ss[tid >> 1];
    b4u r4;
    r4.h[0] = __float2bfloat16(w4.x * sc);
    r4.h[1] = __float2bfloat16(w4.y * sc);
    r4.h[2] = __float2bfloat16(w4.z * sc);
    r4.h[3] = __float2bfloat16(w4.w * sc);
    const size_t rowb = (size_t)o * KTOT;
    *(ushort2*)(B + rowb + INF + (size_t)r * 4)     = r4.v2[0];
    *(ushort2*)(B + rowb + INF + (size_t)r * 4 + 2) = r4.v2[1];
    if ((tid & 1) == 0)
      B[rowb + (r >> 1)] = __float2bfloat16(bw[tid >> 1]);
  }
}

// ---------------- GEMM: C = [A_base(x)|spline(x)] [M,K] * B[N,K]^T -----------------
// R7 loop (1-barrier/K-tile, counted lgkm+vmcnt, 3-ring, XCD remap, k-slice wave
// pairs; gemm 150us verified PASS) with ONE change: spline A-tiles (kt>=16) are
// PRODUCED in-kernel instead of staged from HBM.
//   thread t owns 4 chunks (rows t>>3 + 64d, slot t&7); content k-chunk
//   kc = (t&7)^(row&7) (verified content-swizzle); chunk = 8 g-values of
//   i = (kt-16)*8 + kc from ONE x value (min-form, R2/R3-validated bit-identical):
//   exp(-|x-g|) = min(e^-x*e^g, e^x*e^-g). ds_write_b128 at t*16 — identical
//   addresses to STAGE_A's dest. x prefetched one FULL ITERATION ahead (~2500cy
//   >> 900cy HBM) into parity-named regs (rule #20).
// lgkm ledger per iter: [4 ds_writes (produce)] + [12 ds_reads] in order;
//   lgkm(4) -> writes + read-group0 retired; lgkm(0) -> all. Same counts as R7.
// vm ledger per iter (issue order: 2 B-stages, [4 A-stages], [4 x-dwords]):
//   boundary vmcnt = #ops issued this iter: kt==13 -> 10; kt<=140 -> 6;
//   kt==141 -> 2; else 0. Produce's x-use auto-waits (compiler) at vmcnt(6)
//   equivalent — its loads are one full iteration old, no stall.
// Cross-wave: produce(kt+2) writes slot pb after the barrier that followed tile
//   kt-1's lgkm(0)-retired reads of that slot. Readers of tile kt+2 run two
//   barriers later. SAFE (same argument as staged path).
#define BM 256
#define BN 128
#define BK 64
#define NT (KTOT / BK)            // 144
#define NBASE (INF / BK)          // 16
#define LDSA (BM * BK * 2)        // 32768 B
#define LDSB (BN * BK * 2)        // 16384 B
#define LDSBUF (LDSA + LDSB)      // 49152 B

__global__ __launch_bounds__(512) void gemm_fused(const float* __restrict__ x,
                                                  const bf16* __restrict__ A,
                                                  const bf16* __restrict__ B,
                                                  float* __restrict__ C) {
  __shared__ __align__(16) char smem[3 * LDSBUF];   // 144 KB ring (+epilogue merge)
  const int t = threadIdx.x;
  const int lane = t & 63;
  const int w = t >> 6;            // wave 0..7
  const int q = w & 3;             // quadrant 0..3 (2M x 2N of 128x64)
  const int s = w >> 2;            // k-slice 0/1 (kk = s*32)
  const int wm = (q >> 1) * 128;   // 0,128
  const int wn = (q & 1) * 64;     // 0,64
  // XCD-aware remap: xcd = lid&7 gets br 4*xcd..4*xcd+3, all bc (L2 reuse of A/x).
  const int lid = blockIdx.y * 8 + blockIdx.x;
  const int br = (lid & 7) * 4 + ((lid >> 3) & 3); // M tile (0..31)
  const int bc = lid >> 5;                         // N tile (0..7)

  const int srow = t >> 3;                         // 0..63
  const int scol = ((t & 7) ^ (srow & 7)) * 8;     // swizzled source k-offset (elems)
  const bf16* gA = A + (size_t)(br * BM + srow) * INF + scol;   // A_base stride INF
  const bf16* gB = B + (size_t)(bc * BN + srow) * KTOT + scol;
  const int wb = w * 1024;

  // ---- produce mapping (spline tiles) ----
  const int arow = t >> 3;                         // 0..63 (+64d)
  const int akc = (t & 7) ^ (arow & 7);            // content k-chunk = i-offset
  const float* xrow = x + (size_t)(br * BM + arow) * INF;
  const float EG[8]  = {0.36787944f, 0.47236655f, 0.60653066f, 0.77880078f,
                        1.0f, 1.28402542f, 1.64872127f, 2.11700002f};   // e^{g_v}
  const float EIG[8] = {2.71828183f, 2.11700002f, 1.64872127f, 1.28402542f,
                        1.0f, 0.77880078f, 0.60653066f, 0.47236655f};   // e^{-g_v}

  // fragment addressing (verified; k-base wave-uniform s*32)
  const int frow = lane & 15;
  const int fk = (lane >> 4) * 8;
  const int fsw = frow & 7;
  const int swk = ((((s << 5) + fk) >> 3) ^ fsw) * 8;

  f32x4_t acc[8][4] = {};
  float xe[4], xo[4];   // x prefetch, parity-named

#define STAGE_A(b_, i_, kt_) \
  __builtin_amdgcn_global_load_lds( \
      (const __attribute__((address_space(1))) void*)(gA + (size_t)(i_) * 64 * INF + (size_t)(kt_) * BK), \
      (__attribute__((address_space(3))) void*)(smem + (b_) * LDSBUF + (i_) * 8192 + wb), 16, 0, 0)
#define STAGE_B(b_, i_, kt_) \
  __builtin_amdgcn_global_load_lds( \
      (const __attribute__((address_space(1))) void*)(gB + (size_t)(i_) * 64 * KTOT + (size_t)(kt_) * BK), \
      (__attribute__((address_space(3))) void*)(smem + (b_) * LDSBUF + LDSA + (i_) * 8192 + wb), 16, 0, 0)

#define XLOAD(dst_, ktp_) do { \
    const int ib_ = ((ktp_) - NBASE) * 8 + akc; \
    dst_[0] = xrow[ib_]; \
    dst_[1] = xrow[(size_t)64 * INF + ib_]; \
    dst_[2] = xrow[(size_t)128 * INF + ib_]; \
    dst_[3] = xrow[(size_t)192 * INF + ib_]; \
  } while (0)

#define PRODUCE(pb_, src_) do { \
    _Pragma("unroll") \
    for (int d = 0; d < 4; ++d) { \
      const float xv_ = src_[d]; \
      const float en_ = __expf(-xv_); \
      const float ep_ = __expf(xv_); \
      b8u pk_; \
      _Pragma("unroll") \
      for (int g = 0; g < 8; ++g) \
        pk_.h[g] = __float2bfloat16(fminf(en_ * EG[g], ep_ * EIG[g])); \
      *(bf16x8_t*)(smem + (pb_) * LDSBUF + d * 8192 + t * 16) = pk_.v; \
    } \
  } while (0)

#define BODY(KT_, XLD_, XPR_) do {                                                 \
    const bf16* sAc = (const bf16*)(smem + cb * LDSBUF);                           \
    const bf16* sBc = (const bf16*)(smem + cb * LDSBUF + LDSA);                    \
    const int pb = (cb == 0) ? 2 : cb - 1;           /* slot of tile KT_+2 */      \
    const bool stB = (KT_) + 2 < NT;                                               \
    const bool stA = (KT_) + 2 < NBASE;                                            \
    const bool px  = (KT_) >= NBASE - 3 && (KT_) <= NT - 4;  /* x for KT_+3 */     \
    const bool pr  = ((KT_) + 2 >= NBASE) && ((KT_) + 2 < NT);                     \
    if (stB) { STAGE_B(pb, 0, (KT_) + 2); STAGE_B(pb, 1, (KT_) + 2); }             \
    if (stA) { STAGE_A(pb, 0, (KT_) + 2); STAGE_A(pb, 1, (KT_) + 2);               \
               STAGE_A(pb, 2, (KT_) + 2); STAGE_A(pb, 3, (KT_) + 2); }             \
    if (px) XLOAD(XLD_, (KT_) + 3);                                                \
    if (pr) PRODUCE(pb, XPR_);   /* 4 ds_writes, oldest in lgkm queue */           \
    bf16x8_t a_lo[4], a_hi[4], bfr[4];                                             \
    _Pragma("unroll")                                                              \
    for (int i = 0; i < 4; ++i) {                                                  \
      a_lo[i] = *(const bf16x8_t*)(sAc + (wm + i * 16 + frow) * BK + swk);         \
      bfr[i]  = *(const bf16x8_t*)(sBc + (wn + i * 16 + frow) * BK + swk);         \
    }                                                                              \
    __builtin_amdgcn_sched_barrier(0);                                             \
    _Pragma("unroll")                                                              \
    for (int i = 0; i < 4; ++i)                                                    \
      a_hi[i] = *(const bf16x8_t*)(sAc + (wm + 64 + i * 16 + frow) * BK + swk);    \
    asm volatile("s_waitcnt lgkmcnt(4)" ::: "memory");  /* writes+group0 done */   \
    __builtin_amdgcn_sched_barrier(0);                                             \
    __builtin_amdgcn_s_setprio(1);                                                 \
    _Pragma("unroll")                                                              \
    for (int i = 0; i < 4; ++i)                                                    \
      _Pragma("unroll")                                                            \
      for (int j = 0; j < 4; ++j)                                                  \
        acc[i][j] = __builtin_amdgcn_mfma_f32_16x16x32_bf16(a_lo[i], bfr[j], acc[i][j], 0, 0, 0); \
    __builtin_amdgcn_s_setprio(0);                                                 \
    asm volatile("s_waitcnt lgkmcnt(0)" ::: "memory");                             \
    __builtin_amdgcn_sched_barrier(0);                                             \
    __builtin_amdgcn_s_setprio(1);                                                 \
    _Pragma("unroll")                                                              \
    for (int i = 0; i < 4; ++i)                                                    \
      _Pragma("unroll")                                                            \
      for (int j = 0; j < 4; ++j)                                                  \
        acc[i + 4][j] = __builtin_amdgcn_mfma_f32_16x16x32_bf16(a_hi[i], bfr[j], acc[i + 4][j], 0, 0, 0); \
    __builtin_amdgcn_s_setprio(0);                                                 \
    /* boundary: vmcnt = #vm ops issued THIS iter (2B +4A +4x by region) */        \
    if ((KT_) == NBASE - 3)      { asm volatile("s_waitcnt vmcnt(10)" ::: "memory"); } \
    else if ((KT_) <= NT - 4)    { asm volatile("s_waitcnt vmcnt(6)"  ::: "memory"); } \
    else if ((KT_) == NT - 3)    { asm volatile("s_waitcnt vmcnt(2)"  ::: "memory"); } \
    else                         { asm volatile("s_waitcnt vmcnt(0)"  ::: "memory"); } \
    __builtin_amdgcn_s_barrier();                                                  \
    cb = (cb == 2) ? 0 : cb + 1;                                                   \
  } while (0)

  // prologue: tiles 0,1 (both in base region) staged exactly as R7
  STAGE_A(0, 0, 0); STAGE_A(0, 1, 0); STAGE_A(0, 2, 0); STAGE_A(0, 3, 0);
  STAGE_B(0, 0, 0); STAGE_B(0, 1, 0);
  STAGE_A(1, 0, 1); STAGE_A(1, 1, 1); STAGE_A(1, 2, 1); STAGE_A(1, 3, 1);
  STAGE_B(1, 0, 1); STAGE_B(1, 1, 1);
  asm volatile("s_waitcnt vmcnt(6)" ::: "memory");   // tile 0 resident
  __builtin_amdgcn_s_barrier();

  int cb = 0;
  for (int kt = 0; kt < NT; kt += 2) {   // NT=144 even
    BODY(kt,     xe, xo);   // XLOAD->xe (if active), PRODUCE reads xo (prev iter)
    BODY(kt + 1, xo, xe);
  }

  // ---- epilogue: merge k-slice pairs via LDS (R7 verbatim) ----
  if (s == 1) {
    char* dst = smem + q * 32768;
    #pragma unroll
    for (int i = 0; i < 8; ++i)
      #pragma unroll
      for (int j = 0; j < 4; ++j)
        *(f32x4_t*)(dst + ((i * 4 + j) * 64 + lane) * 16) = acc[i][j];
  }
  __syncthreads();
  if (s == 0) {
    const char* src = smem + q * 32768;
    #pragma unroll
    for (int i = 0; i < 8; ++i)
      #pragma unroll
      for (int j = 0; j < 4; ++j) {
        const f32x4_t p = *(const f32x4_t*)(src + ((i * 4 + j) * 64 + lane) * 16);
        acc[i][j] += p;
      }
    const int ccol = bc * BN + wn + frow;
    const int crow0 = br * BM + wm + (lane >> 4) * 4;
    #pragma unroll
    for (int i = 0; i < 8; ++i)
      #pragma unroll
      for (int r = 0; r < 4; ++r) {
        float* cp = C + (size_t)(crow0 + i * 16 + r) * OUTF + ccol;
        #pragma unroll
        for (int j = 0; j < 4; ++j)
          cp[j * 16] = acc[i][j][r];
      }
  }
#undef STAGE_A
#undef STAGE_B
#undef XLOAD
#undef PRODUCE
#undef BODY
}

// ---------------- fallback (ws too small): naive, correctness-only ----------------
__global__ __launch_bounds__(256) void naive_kern(const float* __restrict__ x,
                                                  const float* __restrict__ bw,
                                                  const float* __restrict__ sw,
                                                  const float* __restrict__ ss,
                                                  const float* __restrict__ grid,
                                                  float* __restrict__ out) {
  const int idx = blockIdx.x * 256 + threadIdx.x;  // n*OUTF + o
  const int o = idx & (OUTF - 1);
  const int n = idx >> 10;
  float acc = 0.f;
  for (int i = 0; i < INF; ++i) {
    const float xv = x[n * INF + i];
    const float s = xv / (1.f + __expf(-xv));
    acc += s * bw[o * INF + i];
    const float sc = ss[o * INF + i];
    #pragma unroll
    for (int g = 0; g < 8; ++g) {
      const float gv = grid[i * 8 + g];
      acc += __expf(-fabsf(xv - gv)) * sw[(size_t)(o * INF + i) * 8 + g] * sc;
    }
  }
  out[idx] = acc;
}

extern "C" void kernel_launch(void* const* d_in, const int* in_sizes, int n_in,
                              void* d_out, int out_size, void* d_ws, size_t ws_size,
                              hipStream_t stream) {
  const float* x    = (const float*)d_in[0];
  const float* bw   = (const float*)d_in[1];
  const float* sw   = (const float*)d_in[2];
  const float* ss   = (const float*)d_in[3];
  const float* grid = (const float*)d_in[4];
  float* out = (float*)d_out;

  const size_t needA = (size_t)NTOK * INF * sizeof(bf16);   // ~16.8 MB (base only)
  const size_t needB = (size_t)OUTF * KTOT * sizeof(bf16);  // ~18.9 MB

  if (ws_size >= needA + needB) {
    bf16* A = (bf16*)d_ws;
    bf16* B = (bf16*)((char*)d_ws + needA);
    prep_fused<<<PA + PB, 256, 0, stream>>>(x, bw, sw, ss, A, B);
    dim3 g(OUTF / BN, NTOK / BM);  // (8, 32) = 256 blocks = 1/CU
    gemm_fused<<<g, 512, 0, stream>>>(x, A, B, out);
  } else {
    naive_kern<<<(NTOK * OUTF) / 256, 256, 0, stream>>>(x, bw, sw, ss, grid, out);
  }
}

// Round 9
// 266.569 us; speedup vs baseline: 1.2512x; 1.2512x over previous
//
#include <hip/hip_runtime.h>
#include <hip/hip_bf16.h>

typedef __hip_bfloat16 bf16;
typedef short bf16x8_t __attribute__((ext_vector_type(8)));  // 8 bf16 = 4 VGPRs
typedef short s4_t __attribute__((ext_vector_type(4)));      // 4 bf16 = 8B
typedef float f32x4_t __attribute__((ext_vector_type(4)));

#define NTOK 8192
#define INF  1024
#define OUTF 1024
#define GS   8
#define KTOT (INF + INF * GS)  // 9216

union b8u { bf16 h[8]; bf16x8_t v; };
union b4u { bf16 h[4]; ushort2 v2[2]; };
union b4s { bf16 h[4]; s4_t v; };

// ---------------- fused prep v3: full-density stores --------------------------------
// A-part: ONE ROW PER BLOCK (block = n); thread t owns i = t + 256j (j=0..3).
//   Every store inst is wave-contiguous: silu 2B/lane (128B/wave), spline 16B/lane
//   (1KB/wave, lane i -> byte i*16 consecutive). R3's layout had thread t own 4
//   CONSECUTIVE i -> 64B-stride lanes (25% line density) on the dominant 134MB
//   spline stream; that pattern measured ~2.7 TB/s effective. Math identical
//   (min-form, validated R3/R6/R7): exp(-|x-g|) = min(e^-x*e^g, e^x*e^-g).
// B-part: verbatim validated prep_b body.
#define PA2 NTOK                      // 8192 row blocks
#define PB ((OUTF * INF * 2) / 256)   // 8192 blocks

__global__ __launch_bounds__(256) void prep_fused(const float* __restrict__ x,
                                                  const float* __restrict__ bw,
                                                  const float* __restrict__ sw,
                                                  const float* __restrict__ ss,
                                                  bf16* __restrict__ A,
                                                  bf16* __restrict__ B) {
  const int b = blockIdx.x;
  if (b < PA2) {
    const float EG[8]  = {0.36787944f, 0.47236655f, 0.60653066f, 0.77880078f,
                          1.0f, 1.28402542f, 1.64872127f, 2.11700002f};   // e^{g_v}
    const float EIG[8] = {2.71828183f, 2.11700002f, 1.64872127f, 1.28402542f,
                          1.0f, 0.77880078f, 0.60653066f, 0.47236655f};   // e^{-g_v}
    const int n = b;
    const size_t rowb = (size_t)n * KTOT;
    #pragma unroll
    for (int j = 0; j < 4; ++j) {
      const int i = threadIdx.x + 256 * j;
      const float xv = x[(size_t)n * INF + i];
      const float en = __expf(-xv);
      const float ep = __expf(xv);
      A[rowb + i] = __float2bfloat16(xv / (1.0f + en));   // SiLU, 128B/wave store
      b8u kn;
      #pragma unroll
      for (int g = 0; g < 8; ++g)
        kn.h[g] = __float2bfloat16(fminf(en * EG[g], ep * EIG[g]));
      *(bf16x8_t*)(A + rowb + INF + (size_t)i * 8) = kn.v; // 1KB/wave store
    }
  } else {
    const int tid = (b - PA2) * 256 + threadIdx.x;  // 0 .. OUTF*INF*2-1
    const int o = tid >> 11;
    const int r = tid & 2047;
    const float4 w4 = ((const float4*)sw)[tid];
    const float sc = ss[tid >> 1];
    b4u r4;
    r4.h[0] = __float2bfloat16(w4.x * sc);
    r4.h[1] = __float2bfloat16(w4.y * sc);
    r4.h[2] = __float2bfloat16(w4.z * sc);
    r4.h[3] = __float2bfloat16(w4.w * sc);
    const size_t rowb = (size_t)o * KTOT;
    *(ushort2*)(B + rowb + INF + (size_t)r * 4)     = r4.v2[0];
    *(ushort2*)(B + rowb + INF + (size_t)r * 4 + 2) = r4.v2[1];
    if ((tid & 1) == 0)
      B[rowb + (r >> 1)] = __float2bfloat16(bw[tid >> 1]);
  }
}

// ---------------- GEMM: C[M,N] = A[M,K] * B[N,K]^T ---------------------------------
// R7 kernel VERBATIM (best measured: ~150us gemm, PASS). 1-barrier/K-tile, counted
// lgkm+vmcnt, 3-ring, XCD remap, k-slice wave pairs (4 quadrants 128x64 x 2 slices),
// acc[8][4], LDS pair-merge epilogue. Fusion variants measured worse 3x (R2/R5/R8).
#define BM 256
#define BN 128
#define BK 64
#define NT (KTOT / BK)            // 144
#define LDSA (BM * BK * 2)        // 32768 B
#define LDSB (BN * BK * 2)        // 16384 B
#define LDSBUF (LDSA + LDSB)      // 49152 B

__global__ __launch_bounds__(512) void gemm_bt2(const bf16* __restrict__ A,
                                                const bf16* __restrict__ B,
                                                float* __restrict__ C) {
  __shared__ __align__(16) char smem[3 * LDSBUF];   // 144 KB ring (+epilogue merge)
  const int t = threadIdx.x;
  const int lane = t & 63;
  const int w = t >> 6;            // wave 0..7
  const int q = w & 3;             // quadrant 0..3 (2M x 2N of 128x64)
  const int s = w >> 2;            // k-slice 0/1 (kk = s*32)
  const int wm = (q >> 1) * 128;   // 0,128
  const int wn = (q & 1) * 64;     // 0,64
  // XCD-aware remap (bijective on 0..255): xcd = lid&7 gets br 4*xcd..4*xcd+3, all bc.
  const int lid = blockIdx.y * 8 + blockIdx.x;     // linear id, x fastest
  const int br = (lid & 7) * 4 + ((lid >> 3) & 3); // M tile (0..31)
  const int bc = lid >> 5;                         // N tile (0..7)

  const int srow = t >> 3;                         // 0..63
  const int scol = ((t & 7) ^ (srow & 7)) * 8;     // swizzled source k-offset (elems)
  const bf16* gA = A + (size_t)(br * BM + srow) * KTOT + scol;
  const bf16* gB = B + (size_t)(bc * BN + srow) * KTOT + scol;
  const int wb = w * 1024;                         // wave's 64 lanes x 16B

  // fragment addressing (verified formula; k-base wave-uniform s*32)
  const int frow = lane & 15;
  const int fk = (lane >> 4) * 8;
  const int fsw = frow & 7;
  const int swk = ((((s << 5) + fk) >> 3) ^ fsw) * 8;   // this wave's k-slice offset

  f32x4_t acc[8][4] = {};

#define STAGE_A(b_, i_, kt_) \
  __builtin_amdgcn_global_load_lds( \
      (const __attribute__((address_space(1))) void*)(gA + (size_t)(i_) * 64 * KTOT + (size_t)(kt_) * BK), \
      (__attribute__((address_space(3))) void*)(smem + (b_) * LDSBUF + (i_) * 8192 + wb), 16, 0, 0)
#define STAGE_B(b_, i_, kt_) \
  __builtin_amdgcn_global_load_lds( \
      (const __attribute__((address_space(1))) void*)(gB + (size_t)(i_) * 64 * KTOT + (size_t)(kt_) * BK), \
      (__attribute__((address_space(3))) void*)(smem + (b_) * LDSBUF + LDSA + (i_) * 8192 + wb), 16, 0, 0)

  // prologue: tile 0 -> buf0, tile 1 -> buf1 (12 loads in flight)
  STAGE_A(0, 0, 0); STAGE_A(0, 1, 0); STAGE_A(0, 2, 0); STAGE_A(0, 3, 0);
  STAGE_B(0, 0, 0); STAGE_B(0, 1, 0);
  STAGE_A(1, 0, 1); STAGE_A(1, 1, 1); STAGE_A(1, 2, 1); STAGE_A(1, 3, 1);
  STAGE_B(1, 0, 1); STAGE_B(1, 1, 1);
  asm volatile("s_waitcnt vmcnt(6)" ::: "memory");   // tile 0 resident
  __builtin_amdgcn_s_barrier();

  int cb = 0;
  for (int kt = 0; kt < NT; ++kt) {
    const bf16* sAc = (const bf16*)(smem + cb * LDSBUF);
    const bf16* sBc = (const bf16*)(smem + cb * LDSBUF + LDSA);
    const int pb = (cb == 0) ? 2 : cb - 1;           // (kt+2)%3
    const bool pf = kt < NT - 2;

    // stages for tile kt+2 (vm-only; earliest issue = max slack)
    if (pf) {
      STAGE_A(pb, 0, kt + 2); STAGE_A(pb, 1, kt + 2);
      STAGE_A(pb, 2, kt + 2); STAGE_A(pb, 3, kt + 2);
      STAGE_B(pb, 0, kt + 2); STAGE_B(pb, 1, kt + 2);
    }

    bf16x8_t a_lo[4], a_hi[4], bfr[4];
    // ---- read group 0: a[0..3] + b[0..3] (oldest 8 in lgkm queue) ----
    #pragma unroll
    for (int i = 0; i < 4; ++i) {
      a_lo[i] = *(const bf16x8_t*)(sAc + (wm + i * 16 + frow) * BK + swk);
      bfr[i]  = *(const bf16x8_t*)(sBc + (wn + i * 16 + frow) * BK + swk);
    }
    __builtin_amdgcn_sched_barrier(0);   // pin group boundary (lgkm(4) semantics)
    // ---- read group 1: a[4..7] (newest 4) ----
    #pragma unroll
    for (int i = 0; i < 4; ++i)
      a_hi[i] = *(const bf16x8_t*)(sAc + (wm + 64 + i * 16 + frow) * BK + swk);
    asm volatile("s_waitcnt lgkmcnt(4)" ::: "memory");  // group 0 retired
    __builtin_amdgcn_sched_barrier(0);
    __builtin_amdgcn_s_setprio(1);
    #pragma unroll
    for (int i = 0; i < 4; ++i)
      #pragma unroll
      for (int j = 0; j < 4; ++j)
        acc[i][j] = __builtin_amdgcn_mfma_f32_16x16x32_bf16(a_lo[i], bfr[j], acc[i][j], 0, 0, 0);
    __builtin_amdgcn_s_setprio(0);
    asm volatile("s_waitcnt lgkmcnt(0)" ::: "memory");  // group 1 (drained under MFMA0)
    __builtin_amdgcn_sched_barrier(0);
    __builtin_amdgcn_s_setprio(1);
    #pragma unroll
    for (int i = 0; i < 4; ++i)
      #pragma unroll
      for (int j = 0; j < 4; ++j)
        acc[i + 4][j] = __builtin_amdgcn_mfma_f32_16x16x32_bf16(a_hi[i], bfr[j], acc[i + 4][j], 0, 0, 0);
    __builtin_amdgcn_s_setprio(0);
    // boundary: counted wait (tile kt+1's stages older than the 6 just issued)
    if (pf) { asm volatile("s_waitcnt vmcnt(6)" ::: "memory"); }
    else    { asm volatile("s_waitcnt vmcnt(0)" ::: "memory"); }
    __builtin_amdgcn_s_barrier();

    cb = (cb == 2) ? 0 : cb + 1;
  }

  // ---- epilogue: merge k-slice pairs via LDS (ring no longer live) ----
  if (s == 1) {
    char* dst = smem + q * 32768;
    #pragma unroll
    for (int i = 0; i < 8; ++i)
      #pragma unroll
      for (int j = 0; j < 4; ++j)
        *(f32x4_t*)(dst + ((i * 4 + j) * 64 + lane) * 16) = acc[i][j];
  }
  __syncthreads();
  if (s == 0) {
    const char* src = smem + q * 32768;
    #pragma unroll
    for (int i = 0; i < 8; ++i)
      #pragma unroll
      for (int j = 0; j < 4; ++j) {
        const f32x4_t p = *(const f32x4_t*)(src + ((i * 4 + j) * 64 + lane) * 16);
        acc[i][j] += p;
      }
    // D mapping col = lane&15, row = (lane>>4)*4 + reg  [m89/m91]
    const int ccol = bc * BN + wn + frow;
    const int crow0 = br * BM + wm + (lane >> 4) * 4;
    #pragma unroll
    for (int i = 0; i < 8; ++i)
      #pragma unroll
      for (int r = 0; r < 4; ++r) {
        float* cp = C + (size_t)(crow0 + i * 16 + r) * OUTF + ccol;
        #pragma unroll
        for (int j = 0; j < 4; ++j)
          cp[j * 16] = acc[i][j][r];
      }
  }
#undef STAGE_A
#undef STAGE_B
}

// ---------------- fallback (ws too small): naive, correctness-only ----------------
__global__ __launch_bounds__(256) void naive_kern(const float* __restrict__ x,
                                                  const float* __restrict__ bw,
                                                  const float* __restrict__ sw,
                                                  const float* __restrict__ ss,
                                                  const float* __restrict__ grid,
                                                  float* __restrict__ out) {
  const int idx = blockIdx.x * 256 + threadIdx.x;  // n*OUTF + o
  const int o = idx & (OUTF - 1);
  const int n = idx >> 10;
  float acc = 0.f;
  for (int i = 0; i < INF; ++i) {
    const float xv = x[n * INF + i];
    const float s = xv / (1.f + __expf(-xv));
    acc += s * bw[o * INF + i];
    const float sc = ss[o * INF + i];
    #pragma unroll
    for (int g = 0; g < 8; ++g) {
      const float gv = grid[i * 8 + g];
      acc += __expf(-fabsf(xv - gv)) * sw[(size_t)(o * INF + i) * 8 + g] * sc;
    }
  }
  out[idx] = acc;
}

extern "C" void kernel_launch(void* const* d_in, const int* in_sizes, int n_in,
                              void* d_out, int out_size, void* d_ws, size_t ws_size,
                              hipStream_t stream) {
  const float* x    = (const float*)d_in[0];
  const float* bw   = (const float*)d_in[1];
  const float* sw   = (const float*)d_in[2];
  const float* ss   = (const float*)d_in[3];
  const float* grid = (const float*)d_in[4];
  float* out = (float*)d_out;

  const size_t needA = (size_t)NTOK * KTOT * sizeof(bf16);  // ~151 MB
  const size_t needB = (size_t)OUTF * KTOT * sizeof(bf16);  // ~19 MB

  if (ws_size >= needA + needB) {
    bf16* A = (bf16*)d_ws;
    bf16* B = (bf16*)((char*)d_ws + needA);
    prep_fused<<<PA2 + PB, 256, 0, stream>>>(x, bw, sw, ss, A, B);
    dim3 g(OUTF / BN, NTOK / BM);  // (8, 32) = 256 blocks = 1/CU
    gemm_bt2<<<g, 512, 0, stream>>>(A, B, out);
  } else {
    naive_kern<<<(NTOK * OUTF) / 256, 256, 0, stream>>>(x, bw, sw, ss, grid, out);
  }
}

// Round 10
// 251.488 us; speedup vs baseline: 1.3262x; 1.0600x over previous
//
#include <hip/hip_runtime.h>
#include <hip/hip_bf16.h>

typedef __hip_bfloat16 bf16;
typedef short bf16x8_t __attribute__((ext_vector_type(8)));  // 8 bf16 = 4 VGPRs
typedef short s4_t __attribute__((ext_vector_type(4)));      // 4 bf16 = 8B
typedef float f32x4_t __attribute__((ext_vector_type(4)));

#define NTOK 8192
#define INF  1024
#define OUTF 1024
#define GS   8
#define KTOT (INF + INF * GS)  // 9216

union b8u { bf16 h[8]; bf16x8_t v; };
union b4u { bf16 h[4]; ushort2 v2[2]; };
union b4s { bf16 h[4]; s4_t v; };

// ---------------- fused prep v3 (R9 VERBATIM — measured good) ----------------------
#define PA2 NTOK                      // 8192 row blocks
#define PB ((OUTF * INF * 2) / 256)   // 8192 blocks

__global__ __launch_bounds__(256) void prep_fused(const float* __restrict__ x,
                                                  const float* __restrict__ bw,
                                                  const float* __restrict__ sw,
                                                  const float* __restrict__ ss,
                                                  bf16* __restrict__ A,
                                                  bf16* __restrict__ B) {
  const int b = blockIdx.x;
  if (b < PA2) {
    const float EG[8]  = {0.36787944f, 0.47236655f, 0.60653066f, 0.77880078f,
                          1.0f, 1.28402542f, 1.64872127f, 2.11700002f};   // e^{g_v}
    const float EIG[8] = {2.71828183f, 2.11700002f, 1.64872127f, 1.28402542f,
                          1.0f, 0.77880078f, 0.60653066f, 0.47236655f};   // e^{-g_v}
    const int n = b;
    const size_t rowb = (size_t)n * KTOT;
    #pragma unroll
    for (int j = 0; j < 4; ++j) {
      const int i = threadIdx.x + 256 * j;
      const float xv = x[(size_t)n * INF + i];
      const float en = __expf(-xv);
      const float ep = __expf(xv);
      A[rowb + i] = __float2bfloat16(xv / (1.0f + en));   // SiLU, 128B/wave store
      b8u kn;
      #pragma unroll
      for (int g = 0; g < 8; ++g)
        kn.h[g] = __float2bfloat16(fminf(en * EG[g], ep * EIG[g]));
      *(bf16x8_t*)(A + rowb + INF + (size_t)i * 8) = kn.v; // 1KB/wave store
    }
  } else {
    const int tid = (b - PA2) * 256 + threadIdx.x;  // 0 .. OUTF*INF*2-1
    const int o = tid >> 11;
    const int r = tid & 2047;
    const float4 w4 = ((const float4*)sw)[tid];
    const float sc = ss[tid >> 1];
    b4u r4;
    r4.h[0] = __float2bfloat16(w4.x * sc);
    r4.h[1] = __float2bfloat16(w4.y * sc);
    r4.h[2] = __float2bfloat16(w4.z * sc);
    r4.h[3] = __float2bfloat16(w4.w * sc);
    const size_t rowb = (size_t)o * KTOT;
    *(ushort2*)(B + rowb + INF + (size_t)r * 4)     = r4.v2[0];
    *(ushort2*)(B + rowb + INF + (size_t)r * 4 + 2) = r4.v2[1];
    if ((tid & 1) == 0)
      B[rowb + (r >> 1)] = __float2bfloat16(bw[tid >> 1]);
  }
}

// ---------------- GEMM: C[M,N] = A[M,K] * B[N,K]^T ---------------------------------
// R7/R9 base (k-slice wave pairs, 3-ring, counted vmcnt, XCD remap; 150.9us/1025TF)
// with ONE structural change: REGISTER-FRAG PREFETCH (distance-1), mid-iter boundary.
//   Iter kt begins with frags(kt) ALREADY IN REGS (read during iter kt-1):
//     stages(kt+2) -> MFMA cluster0 [no lgkm wait] -> vmcnt(6)+BARRIER (tile kt+1
//     published; boundary moved end->mid) -> issue 12 reads frags(kt+1) ->
//     MFMA cluster1 [reads drain under it] -> lgkm(0) [mostly drained].
//   MFMA never waits on same-iter LDS reads; LDS pipe streams a full iteration.
// Hazard ledger:
//   - WAR ring: stages(kt+2) (issued top iter kt) overwrite buf[(kt-1)%3]; its
//     frags were read mid-iter kt-2, lgkm-retired before end-iter kt-2, i.e.
//     before that wave passed MID-BARRIER(kt-1); stages(kt+2) issue after this
//     wave passed MID-BARRIER(kt-1). Barrier separates. SAFE.
//   - mid vmcnt(6): outstanding = stages(kt+1)[6 old] + stages(kt+2)[6 new] ->
//     retires kt+1's. kt=NT-2: no new stages -> vmcnt(0). kt=NT-1: mid skipped.
//   - reads(kt+1) read buf[(kt+1)%3]; stages in flight target buf[(kt+2)%3]. OK.
//   - sched_barrier(0) after s_barrier: pins ds_reads BEHIND the barrier (this
//     wave's vmcnt only covers its own stages; other waves' rows need barrier).
//   - lgkm(0)+sched_barrier at iter end: next iter's cluster0 (reads these regs)
//     cannot hoist above it (rule #18).
#define BM 256
#define BN 128
#define BK 64
#define NT (KTOT / BK)            // 144
#define LDSA (BM * BK * 2)        // 32768 B
#define LDSB (BN * BK * 2)        // 16384 B
#define LDSBUF (LDSA + LDSB)      // 49152 B

__global__ __launch_bounds__(512) void gemm_bt2(const bf16* __restrict__ A,
                                                const bf16* __restrict__ B,
                                                float* __restrict__ C) {
  __shared__ __align__(16) char smem[3 * LDSBUF];   // 144 KB ring (+epilogue merge)
  const int t = threadIdx.x;
  const int lane = t & 63;
  const int w = t >> 6;            // wave 0..7
  const int q = w & 3;             // quadrant 0..3 (2M x 2N of 128x64)
  const int s = w >> 2;            // k-slice 0/1 (kk = s*32)
  const int wm = (q >> 1) * 128;   // 0,128
  const int wn = (q & 1) * 64;     // 0,64
  // XCD-aware remap (bijective on 0..255): xcd = lid&7 gets br 4*xcd..4*xcd+3, all bc.
  const int lid = blockIdx.y * 8 + blockIdx.x;     // linear id, x fastest
  const int br = (lid & 7) * 4 + ((lid >> 3) & 3); // M tile (0..31)
  const int bc = lid >> 5;                         // N tile (0..7)

  const int srow = t >> 3;                         // 0..63
  const int scol = ((t & 7) ^ (srow & 7)) * 8;     // swizzled source k-offset (elems)
  const bf16* gA = A + (size_t)(br * BM + srow) * KTOT + scol;
  const bf16* gB = B + (size_t)(bc * BN + srow) * KTOT + scol;
  const int wb = w * 1024;                         // wave's 64 lanes x 16B

  // fragment addressing (verified formula; k-base wave-uniform s*32)
  const int frow = lane & 15;
  const int fk = (lane >> 4) * 8;
  const int fsw = frow & 7;
  const int swk = ((((s << 5) + fk) >> 3) ^ fsw) * 8;   // this wave's k-slice offset

  f32x4_t acc[8][4] = {};
  bf16x8_t aLE[4], aHE[4], bE[4];   // frag set E (even tiles)
  bf16x8_t aLO[4], aHO[4], bO[4];   // frag set O (odd tiles)

#define STAGE_A(b_, i_, kt_) \
  __builtin_amdgcn_global_load_lds( \
      (const __attribute__((address_space(1))) void*)(gA + (size_t)(i_) * 64 * KTOT + (size_t)(kt_) * BK), \
      (__attribute__((address_space(3))) void*)(smem + (b_) * LDSBUF + (i_) * 8192 + wb), 16, 0, 0)
#define STAGE_B(b_, i_, kt_) \
  __builtin_amdgcn_global_load_lds( \
      (const __attribute__((address_space(1))) void*)(gB + (size_t)(i_) * 64 * KTOT + (size_t)(kt_) * BK), \
      (__attribute__((address_space(3))) void*)(smem + (b_) * LDSBUF + LDSA + (i_) * 8192 + wb), 16, 0, 0)

#define STAGE6(b_, kt_) do { \
    STAGE_A(b_, 0, kt_); STAGE_A(b_, 1, kt_); \
    STAGE_A(b_, 2, kt_); STAGE_A(b_, 3, kt_); \
    STAGE_B(b_, 0, kt_); STAGE_B(b_, 1, kt_); \
  } while (0)

#define READ12(buf_, AL_, AH_, BB_) do { \
    const bf16* sAr_ = (const bf16*)(smem + (buf_) * LDSBUF); \
    const bf16* sBr_ = (const bf16*)(smem + (buf_) * LDSBUF + LDSA); \
    _Pragma("unroll") \
    for (int i = 0; i < 4; ++i) { \
      AL_[i] = *(const bf16x8_t*)(sAr_ + (wm + i * 16 + frow) * BK + swk); \
      BB_[i] = *(const bf16x8_t*)(sBr_ + (wn + i * 16 + frow) * BK + swk); \
    } \
    _Pragma("unroll") \
    for (int i = 0; i < 4; ++i) \
      AH_[i] = *(const bf16x8_t*)(sAr_ + (wm + 64 + i * 16 + frow) * BK + swk); \
  } while (0)

#define BODY(KT_, CL_, CH_, CB_, NL_, NH_, NB_) do {                               \
    const int pb = (cb == 0) ? 2 : cb - 1;           /* slot of tile KT_+2 */      \
    const int nb = (cb == 2) ? 0 : cb + 1;           /* slot of tile KT_+1 */      \
    if ((KT_) + 2 < NT) STAGE6(pb, (KT_) + 2);                                     \
    __builtin_amdgcn_s_setprio(1);                                                 \
    _Pragma("unroll")                                                              \
    for (int i = 0; i < 4; ++i)                                                    \
      _Pragma("unroll")                                                            \
      for (int j = 0; j < 4; ++j)                                                  \
        acc[i][j] = __builtin_amdgcn_mfma_f32_16x16x32_bf16(CL_[i], CB_[j], acc[i][j], 0, 0, 0); \
    __builtin_amdgcn_s_setprio(0);                                                 \
    if ((KT_) + 1 < NT) {                                                          \
      if ((KT_) + 2 < NT) { asm volatile("s_waitcnt vmcnt(6)" ::: "memory"); }     \
      else                { asm volatile("s_waitcnt vmcnt(0)" ::: "memory"); }     \
      __builtin_amdgcn_s_barrier();                                                \
      __builtin_amdgcn_sched_barrier(0);  /* reads must stay AFTER barrier */      \
      READ12(nb, NL_, NH_, NB_);                                                   \
    }                                                                              \
    __builtin_amdgcn_s_setprio(1);                                                 \
    _Pragma("unroll")                                                              \
    for (int i = 0; i < 4; ++i)                                                    \
      _Pragma("unroll")                                                            \
      for (int j = 0; j < 4; ++j)                                                  \
        acc[i + 4][j] = __builtin_amdgcn_mfma_f32_16x16x32_bf16(CH_[i], CB_[j], acc[i + 4][j], 0, 0, 0); \
    __builtin_amdgcn_s_setprio(0);                                                 \
    asm volatile("s_waitcnt lgkmcnt(0)" ::: "memory");  /* drained under MFMA1 */  \
    __builtin_amdgcn_sched_barrier(0);                                             \
    cb = nb;                                                                       \
  } while (0)

  // prologue: stage tiles 0,1; publish tile 0; preload frags(0) -> set E
  STAGE6(0, 0);
  STAGE6(1, 1);
  asm volatile("s_waitcnt vmcnt(6)" ::: "memory");   // tile 0 resident
  __builtin_amdgcn_s_barrier();
  __builtin_amdgcn_sched_barrier(0);
  READ12(0, aLE, aHE, bE);
  asm volatile("s_waitcnt lgkmcnt(0)" ::: "memory");
  __builtin_amdgcn_sched_barrier(0);

  int cb = 0;
  for (int kt = 0; kt < NT; kt += 2) {   // NT=144 even
    BODY(kt,     aLE, aHE, bE, aLO, aHO, bO);
    BODY(kt + 1, aLO, aHO, bO, aLE, aHE, bE);
  }

  // ---- epilogue: merge k-slice pairs via LDS (R7/R9 verbatim) ----
  if (s == 1) {
    char* dst = smem + q * 32768;
    #pragma unroll
    for (int i = 0; i < 8; ++i)
      #pragma unroll
      for (int j = 0; j < 4; ++j)
        *(f32x4_t*)(dst + ((i * 4 + j) * 64 + lane) * 16) = acc[i][j];
  }
  __syncthreads();
  if (s == 0) {
    const char* src = smem + q * 32768;
    #pragma unroll
    for (int i = 0; i < 8; ++i)
      #pragma unroll
      for (int j = 0; j < 4; ++j) {
        const f32x4_t p = *(const f32x4_t*)(src + ((i * 4 + j) * 64 + lane) * 16);
        acc[i][j] += p;
      }
    // D mapping col = lane&15, row = (lane>>4)*4 + reg  [m89/m91]
    const int ccol = bc * BN + wn + frow;
    const int crow0 = br * BM + wm + (lane >> 4) * 4;
    #pragma unroll
    for (int i = 0; i < 8; ++i)
      #pragma unroll
      for (int r = 0; r < 4; ++r) {
        float* cp = C + (size_t)(crow0 + i * 16 + r) * OUTF + ccol;
        #pragma unroll
        for (int j = 0; j < 4; ++j)
          cp[j * 16] = acc[i][j][r];
      }
  }
#undef STAGE_A
#undef STAGE_B
#undef STAGE6
#undef READ12
#undef BODY
}

// ---------------- fallback (ws too small): naive, correctness-only ----------------
__global__ __launch_bounds__(256) void naive_kern(const float* __restrict__ x,
                                                  const float* __restrict__ bw,
                                                  const float* __restrict__ sw,
                                                  const float* __restrict__ ss,
                                                  const float* __restrict__ grid,
                                                  float* __restrict__ out) {
  const int idx = blockIdx.x * 256 + threadIdx.x;  // n*OUTF + o
  const int o = idx & (OUTF - 1);
  const int n = idx >> 10;
  float acc = 0.f;
  for (int i = 0; i < INF; ++i) {
    const float xv = x[n * INF + i];
    const float s = xv / (1.f + __expf(-xv));
    acc += s * bw[o * INF + i];
    const float sc = ss[o * INF + i];
    #pragma unroll
    for (int g = 0; g < 8; ++g) {
      const float gv = grid[i * 8 + g];
      acc += __expf(-fabsf(xv - gv)) * sw[(size_t)(o * INF + i) * 8 + g] * sc;
    }
  }
  out[idx] = acc;
}

extern "C" void kernel_launch(void* const* d_in, const int* in_sizes, int n_in,
                              void* d_out, int out_size, void* d_ws, size_t ws_size,
                              hipStream_t stream) {
  const float* x    = (const float*)d_in[0];
  const float* bw   = (const float*)d_in[1];
  const float* sw   = (const float*)d_in[2];
  const float* ss   = (const float*)d_in[3];
  const float* grid = (const float*)d_in[4];
  float* out = (float*)d_out;

  const size_t needA = (size_t)NTOK * KTOT * sizeof(bf16);  // ~151 MB
  const size_t needB = (size_t)OUTF * KTOT * sizeof(bf16);  // ~19 MB

  if (ws_size >= needA + needB) {
    bf16* A = (bf16*)d_ws;
    bf16* B = (bf16*)((char*)d_ws + needA);
    prep_fused<<<PA2 + PB, 256, 0, stream>>>(x, bw, sw, ss, A, B);
    dim3 g(OUTF / BN, NTOK / BM);  // (8, 32) = 256 blocks = 1/CU
    gemm_bt2<<<g, 512, 0, stream>>>(A, B, out);
  } else {
    naive_kern<<<(NTOK * OUTF) / 256, 256, 0, stream>>>(x, bw, sw, ss, grid, out);
  }
}